// Round 6
// baseline (955.518 us; speedup 1.0000x reference)
//
#include <hip/hip_runtime.h>

#define N_NODES 100000
#define N_EDGES 1600000
#define M_PAD   100096   // 782 * 128
#define BCAP    64       // bucket capacity per node (Poisson(16): P(>=64) ~ 1e-20)

// mega-prep role partition (block ranges, dispatched in order)
#define EB 3125   // edge blocks: 2 edges/thread * 256 = 512 edges/block * 3125 = 1.6M
#define XB 4096   // cvt_x blocks (grid-stride)
#define WB 416    // weight-transpose blocks (grid-stride over concatenated task list)
#define X_REAL 51200000L          // N_NODES*512 (multiple of 8)
#define X_PAD  ((long)M_PAD*512)
#define WTOT   425984             // total weight elems across all 7 matrices

typedef __bf16 bf16x8 __attribute__((ext_vector_type(8)));
typedef float  f32x4  __attribute__((ext_vector_type(4)));
typedef unsigned short u16x8 __attribute__((ext_vector_type(8)));

__device__ __forceinline__ unsigned short f2bf(float f) {
  union { float f; unsigned u; } x; x.f = f;
  unsigned r = (x.u + 0x7FFFu + ((x.u >> 16) & 1u)) >> 16;
  return (unsigned short)r;
}

__device__ __forceinline__ void async_copy16(const void* g, void* l) {
  __builtin_amdgcn_global_load_lds((__attribute__((address_space(1))) void*)g,
                                   (__attribute__((address_space(3))) void*)l,
                                   16, 0, 0);
}

// ---------------- fused prep: edges + x->bf16 + 7 weight transposes ----------------
// hist[0..N) = cnt_in/deg_in, hist[N..2N) = deg_out (zeroed by exact-size memset before)
__global__ void mega_prep_kernel(const int* __restrict__ src, const int* __restrict__ dst,
                                 int* __restrict__ hist, int* __restrict__ bucket,
                                 const float* __restrict__ x, unsigned short* __restrict__ xb,
                                 const float* __restrict__ W1, unsigned short* __restrict__ W1t,
                                 const float* __restrict__ W2, unsigned short* __restrict__ W2t,
                                 const float* __restrict__ W3, unsigned short* __restrict__ W3t,
                                 const float* __restrict__ Wg1, unsigned short* __restrict__ Wg1t,
                                 const float* __restrict__ Wg2, unsigned short* __restrict__ Wg2t,
                                 const float* __restrict__ Wg3, unsigned short* __restrict__ Wg3t,
                                 const float* __restrict__ Wg4, unsigned short* __restrict__ Wg4t) {
  const int bid = blockIdx.x;
  const int tid = threadIdx.x;
  if (bid < EB) {
    // ---- role E: bucketed adjacency + both degree histograms, 2 edges/thread ----
    int e2 = bid * 256 + tid;
    int2 s2 = ((const int2*)src)[e2];
    int2 d2 = ((const int2*)dst)[e2];
    atomicAdd(&hist[N_NODES + s2.x], 1);
    int p0 = atomicAdd(&hist[d2.x], 1);
    if (p0 < BCAP) bucket[(size_t)d2.x * BCAP + p0] = s2.x;
    atomicAdd(&hist[N_NODES + s2.y], 1);
    int p1 = atomicAdd(&hist[d2.y], 1);
    if (p1 < BCAP) bucket[(size_t)d2.y * BCAP + p1] = s2.y;
  } else if (bid < EB + XB) {
    // ---- role X: x (f32) -> xb (bf16), rows >= N_NODES zero-filled ----
    const long stride = (long)XB * 256 * 8;
    for (long e = ((long)(bid - EB) * 256 + tid) * 8; e < X_PAD; e += stride) {
      u16x8 o;
      if (e < X_REAL) {
        float4 f0 = *(const float4*)(x + e);
        float4 f1 = *(const float4*)(x + e + 4);
        o[0] = f2bf(f0.x); o[1] = f2bf(f0.y); o[2] = f2bf(f0.z); o[3] = f2bf(f0.w);
        o[4] = f2bf(f1.x); o[5] = f2bf(f1.y); o[6] = f2bf(f1.z); o[7] = f2bf(f1.w);
      } else {
        o = (u16x8)0;
      }
      *(u16x8*)(xb + e) = o;
    }
  } else {
    // ---- role W: W[K][N] f32 -> Wt[Npad][K] bf16 (transpose, zero-pad cols>=N) ----
    for (int idx = (bid - EB - XB) * 256 + tid; idx < WTOT; idx += WB * 256) {
      const float* W; unsigned short* Wt; int K, N, local;
      if (idx < 262144)      { W = W1;  Wt = W1t;  K = 512; N = 512; local = idx; }
      else if (idx < 393216) { W = W2;  Wt = W2t;  K = 512; N = 256; local = idx - 262144; }
      else if (idx < 409600) { W = W3;  Wt = W3t;  K = 256; N = 64;  local = idx - 393216; }
      else if (idx < 413696) { W = Wg1; Wt = Wg1t; K = 64;  N = 64;  local = idx - 409600; }
      else if (idx < 417792) { W = Wg2; Wt = Wg2t; K = 64;  N = 64;  local = idx - 413696; }
      else if (idx < 421888) { W = Wg3; Wt = Wg3t; K = 64;  N = 64;  local = idx - 417792; }
      else                   { W = Wg4; Wt = Wg4t; K = 64;  N = 40;  local = idx - 421888; }
      int n = local / K, k = local % K;
      Wt[local] = (n < N) ? f2bf(W[(long)k * N + n]) : (unsigned short)0;
    }
  }
}

__global__ void norms_kernel(const int* __restrict__ hist,
                             float* __restrict__ nsrc, float* __restrict__ ndst) {
  int i = blockIdx.x * 256 + threadIdx.x;
  if (i >= M_PAD) return;
  if (i < N_NODES) {
    nsrc[i] = rsqrtf(fmaxf((float)hist[N_NODES + i], 1.f));  // deg_out
    ndst[i] = rsqrtf(fmaxf((float)hist[i], 1.f));            // deg_in
  } else {
    nsrc[i] = 1.f;
  }
}

// ---------------- GEMM: C = A(bf16,[M_PAD][K]) x Bt(bf16,[Nfull][K])^T ----------------
// EPI 0: bf16( relu(acc + bias[col]) )
// EPI 1: bf16( relu(acc + bias[col]) * rowscale[row] )
// EPI 2: f32 raw acc (no bias)
template <int BM, int BN, int BK, int EPI>
__launch_bounds__(256)
__global__ void gemm_bt(const unsigned short* __restrict__ A,
                        const unsigned short* __restrict__ Bt,
                        const float* __restrict__ bias,
                        const float* __restrict__ rowscale,
                        void* __restrict__ C, int K, int Nfull) {
  constexpr int WM = BM / 2, WN = BN / 2;
  constexpr int MI = WM / 16, NI = WN / 16;
  __shared__ __align__(16) unsigned short As[BM * BK];
  __shared__ __align__(16) unsigned short Bs[BN * BK];
  const int tid = threadIdx.x;
  const int wave = tid >> 6, lane = tid & 63;
  const int wm0 = (wave >> 1) * WM, wn0 = (wave & 1) * WN;
  const long rowBase = (long)blockIdx.y * BM;
  const int colBase = blockIdx.x * BN;
  const unsigned short* Ab = A + rowBase * K;
  const unsigned short* Bb = Bt + (long)colBase * K;
  f32x4 acc[MI][NI] = {};
  constexpr int ACH = BM * BK / 8;  // 16B chunks
  constexpr int BCH = BN * BK / 8;
  for (int k0 = 0; k0 < K; k0 += BK) {
#pragma unroll
    for (int c = tid; c < ACH; c += 256) {
      int r = (c * 8) / BK, cc = (c * 8) % BK;
      async_copy16(Ab + (long)r * K + k0 + cc, &As[c * 8]);
    }
#pragma unroll
    for (int c = tid; c < BCH; c += 256) {
      int r = (c * 8) / BK, cc = (c * 8) % BK;
      async_copy16(Bb + (long)r * K + k0 + cc, &Bs[c * 8]);
    }
    __syncthreads();
#pragma unroll
    for (int kk = 0; kk < BK; kk += 32) {
      bf16x8 af[MI], bfr[NI];
#pragma unroll
      for (int mi = 0; mi < MI; ++mi)
        af[mi] = *(const bf16x8*)&As[(wm0 + mi * 16 + (lane & 15)) * BK + kk + (lane >> 4) * 8];
#pragma unroll
      for (int ni = 0; ni < NI; ++ni)
        bfr[ni] = *(const bf16x8*)&Bs[(wn0 + ni * 16 + (lane & 15)) * BK + kk + (lane >> 4) * 8];
#pragma unroll
      for (int mi = 0; mi < MI; ++mi)
#pragma unroll
        for (int ni = 0; ni < NI; ++ni)
          acc[mi][ni] = __builtin_amdgcn_mfma_f32_16x16x32_bf16(af[mi], bfr[ni], acc[mi][ni], 0, 0, 0);
    }
    __syncthreads();
  }
  const int q = lane >> 4, c15 = lane & 15;
#pragma unroll
  for (int mi = 0; mi < MI; ++mi) {
#pragma unroll
    for (int ni = 0; ni < NI; ++ni) {
#pragma unroll
      for (int r = 0; r < 4; ++r) {
        long row = rowBase + wm0 + mi * 16 + q * 4 + r;
        int col = colBase + wn0 + ni * 16 + c15;
        float v = acc[mi][ni][r];
        if (EPI == 0) {
          v = fmaxf(v + bias[col], 0.f);
          ((unsigned short*)C)[row * Nfull + col] = f2bf(v);
        } else if (EPI == 1) {
          v = fmaxf(v + bias[col], 0.f) * rowscale[row];
          ((unsigned short*)C)[row * Nfull + col] = f2bf(v);
        } else {  // EPI == 2: raw f32
          ((float*)C)[row * Nfull + col] = v;
        }
      }
    }
  }
}

// ---------------- aggregation over f32 t-rows (GEMM-first order) ----------------
// acc = ndst[node] * sum_{s in bucket[node]} t[s][:]  ; v = relu(acc + bias)
// FINAL 0: gout[node][c] = bf16(v * nsrc[node])   (64 cols)
// FINAL 1: dout[node][c] = v                      (40 of 64 cols; t stride stays 64)
template <int FINAL>
__global__ void aggregate_kernel(const float* __restrict__ t,
                                 const int* __restrict__ bucket, const int* __restrict__ cnt,
                                 const float* __restrict__ ndst, const float* __restrict__ nsrc,
                                 const float* __restrict__ bias,
                                 unsigned short* __restrict__ gout, float* __restrict__ dout) {
  int node = blockIdx.x * 4 + (threadIdx.x >> 6);
  int lane = threadIdx.x & 63;
  int r = lane >> 4;
  int c = (lane & 15) * 4;
  int n = min(cnt[node], BCAP);
  const int* bk = bucket + (size_t)node * BCAP;
  float4 acc = make_float4(0.f, 0.f, 0.f, 0.f);
  for (int i = r; i < n; i += 4) {
    int s = bk[i];
    float4 v = *(const float4*)(t + (size_t)s * 64 + c);
    acc.x += v.x; acc.y += v.y; acc.z += v.z; acc.w += v.w;
  }
  acc.x += __shfl_xor(acc.x, 16); acc.y += __shfl_xor(acc.y, 16);
  acc.z += __shfl_xor(acc.z, 16); acc.w += __shfl_xor(acc.w, 16);
  acc.x += __shfl_xor(acc.x, 32); acc.y += __shfl_xor(acc.y, 32);
  acc.z += __shfl_xor(acc.z, 32); acc.w += __shfl_xor(acc.w, 32);
  if (r == 0) {
    float nd = ndst[node];
    float v0 = fmaxf(nd * acc.x + bias[c + 0], 0.f);
    float v1 = fmaxf(nd * acc.y + bias[c + 1], 0.f);
    float v2 = fmaxf(nd * acc.z + bias[c + 2], 0.f);
    float v3 = fmaxf(nd * acc.w + bias[c + 3], 0.f);
    if (FINAL) {
      if (c < 40) {  // c multiple of 4; 40 too, so the quad never straddles
        float* o = dout + (size_t)node * 40;
        o[c + 0] = v0; o[c + 1] = v1; o[c + 2] = v2; o[c + 3] = v3;
      }
    } else {
      float ns = nsrc[node];
      ushort4 o;
      o.x = f2bf(v0 * ns); o.y = f2bf(v1 * ns);
      o.z = f2bf(v2 * ns); o.w = f2bf(v3 * ns);
      *(ushort4*)(gout + (size_t)node * 64 + c) = o;
    }
  }
}

// ---------------- launch ----------------

extern "C" void kernel_launch(void* const* d_in, const int* in_sizes, int n_in,
                              void* d_out, int out_size, void* d_ws, size_t ws_size,
                              hipStream_t stream) {
  (void)in_sizes; (void)n_in; (void)out_size; (void)ws_size;
  const float* x   = (const float*)d_in[0];
  const int* esrc  = (const int*)d_in[1];
  const int* edst  = (const int*)d_in[2];
  const float* W1  = (const float*)d_in[3];  const float* b1  = (const float*)d_in[4];
  const float* W2  = (const float*)d_in[5];  const float* b2  = (const float*)d_in[6];
  const float* W3  = (const float*)d_in[7];  const float* b3  = (const float*)d_in[8];
  const float* Wg1 = (const float*)d_in[9];  const float* bg1 = (const float*)d_in[10];
  const float* Wg2 = (const float*)d_in[11]; const float* bg2 = (const float*)d_in[12];
  const float* Wg3 = (const float*)d_in[13]; const float* bg3 = (const float*)d_in[14];
  const float* Wg4 = (const float*)d_in[15]; const float* bg4 = (const float*)d_in[16];
  float* out = (float*)d_out;

  char* ws = (char*)d_ws;
  size_t off = 0;
  auto alloc = [&](size_t bytes) -> void* {
    void* p = ws + off;
    off += (bytes + 255) & ~(size_t)255;
    return p;
  };

  unsigned short* xb = (unsigned short*)alloc((size_t)M_PAD * 512 * 2);  // region0 (reused)
  unsigned short* h1 = (unsigned short*)alloc((size_t)M_PAD * 512 * 2);
  int*   bucket  = (int*)alloc((size_t)N_NODES * BCAP * 4);
  int*   hist    = (int*)alloc((size_t)2 * N_NODES * 4);  // ONE block, exact memset
  float* nsrc    = (float*)alloc((size_t)M_PAD * 4);
  float* ndst    = (float*)alloc((size_t)N_NODES * 4);
  unsigned short* W1t  = (unsigned short*)alloc(512 * 512 * 2);
  unsigned short* W2t  = (unsigned short*)alloc(256 * 512 * 2);
  unsigned short* W3t  = (unsigned short*)alloc(64 * 256 * 2);
  unsigned short* Wg1t = (unsigned short*)alloc(64 * 64 * 2);
  unsigned short* Wg2t = (unsigned short*)alloc(64 * 64 * 2);
  unsigned short* Wg3t = (unsigned short*)alloc(64 * 64 * 2);
  unsigned short* Wg4t = (unsigned short*)alloc(64 * 64 * 2);

  // region0 reuse (xb dead after layer-1 GEMM); sizes sum to exactly M_PAD*1024 B:
  unsigned short* h2 = xb;                                                     // M_PAD*256 bf16
  unsigned short* ga = (unsigned short*)((char*)xb + (size_t)M_PAD * 256 * 2); // M_PAD*64 bf16
  unsigned short* ab = (unsigned short*)((char*)ga + (size_t)M_PAD * 64 * 2);  // M_PAD*64 bf16
  float*          tb = (float*)((char*)ab + (size_t)M_PAD * 64 * 2);           // M_PAD*64 f32

  // 1) zero both histograms — exact size
  hipMemsetAsync(hist, 0, (size_t)2 * N_NODES * 4, stream);

  // 2) fused prep: edge buckets+degrees || x->bf16 || weight transposes
  mega_prep_kernel<<<EB + XB + WB, 256, 0, stream>>>(
      esrc, edst, hist, bucket, x, xb,
      W1, W1t, W2, W2t, W3, W3t, Wg1, Wg1t, Wg2, Wg2t, Wg3, Wg3t, Wg4, Wg4t);

  // 3) norms
  norms_kernel<<<(M_PAD + 255) / 256, 256, 0, stream>>>(hist, nsrc, ndst);

  const int GY = M_PAD / 128;  // 782

  // 4) MLP (ga = nsrc * relu-chain output, bf16)
  gemm_bt<128, 128, 64, 0><<<dim3(4, GY), 256, 0, stream>>>(xb, W1t, b1, nullptr, h1, 512, 512);
  gemm_bt<128, 128, 64, 0><<<dim3(2, GY), 256, 0, stream>>>(h1, W2t, b2, nullptr, h2, 512, 256);
  gemm_bt<128, 64, 64, 1><<<dim3(1, GY), 256, 0, stream>>>(h2, W3t, b3, nsrc, ga, 256, 64);

  // 5) GCN layers, GEMM-first (f32 t stride 64 ALWAYS, single bf16 rounding per layer):
  //    t = g @ Wg ; g' = bf16( nsrc * relu(ndst * segsum(t[src]) + b) )
  gemm_bt<128, 64, 64, 2><<<dim3(1, GY), 256, 0, stream>>>(ga, Wg1t, nullptr, nullptr, tb, 64, 64);
  aggregate_kernel<0><<<N_NODES / 4, 256, 0, stream>>>(tb, bucket, hist, ndst, nsrc, bg1, ab, nullptr);

  gemm_bt<128, 64, 64, 2><<<dim3(1, GY), 256, 0, stream>>>(ab, Wg2t, nullptr, nullptr, tb, 64, 64);
  aggregate_kernel<0><<<N_NODES / 4, 256, 0, stream>>>(tb, bucket, hist, ndst, nsrc, bg2, ga, nullptr);

  gemm_bt<128, 64, 64, 2><<<dim3(1, GY), 256, 0, stream>>>(ga, Wg3t, nullptr, nullptr, tb, 64, 64);
  aggregate_kernel<0><<<N_NODES / 4, 256, 0, stream>>>(tb, bucket, hist, ndst, nsrc, bg3, ab, nullptr);

  // final: Nfull=64 (padded weight cols are zero; aggregate masks lanes >= 40)
  gemm_bt<128, 64, 64, 2><<<dim3(1, GY), 256, 0, stream>>>(ab, Wg4t, nullptr, nullptr, tb, 64, 64);
  aggregate_kernel<1><<<N_NODES / 4, 256, 0, stream>>>(tb, bucket, hist, ndst, nsrc, bg4, nullptr, out);
}

// Round 7
// 893.890 us; speedup vs baseline: 1.0689x; 1.0689x over previous
//
#include <hip/hip_runtime.h>

#define N_NODES 100000
#define N_EDGES 1600000
#define M_PAD   100096   // 782 * 128
#define BCAP    64       // bucket capacity per node (Poisson(16): P(>=64) ~ 1e-20)
#define X_REAL 51200000L          // N_NODES*512
#define X_PAD  ((long)M_PAD*512)  // 51249152, divisible by 2048

typedef __bf16 bf16x8 __attribute__((ext_vector_type(8)));
typedef float  f32x4  __attribute__((ext_vector_type(4)));
typedef unsigned short u16x8 __attribute__((ext_vector_type(8)));

__device__ __forceinline__ unsigned short f2bf(float f) {
  union { float f; unsigned u; } x; x.f = f;
  unsigned r = (x.u + 0x7FFFu + ((x.u >> 16) & 1u)) >> 16;
  return (unsigned short)r;
}

__device__ __forceinline__ void async_copy16(const void* g, void* l) {
  __builtin_amdgcn_global_load_lds((__attribute__((address_space(1))) void*)g,
                                   (__attribute__((address_space(3))) void*)l,
                                   16, 0, 0);
}

// ---------------- prep kernels ----------------

__global__ void cvt_x_kernel(const float* __restrict__ x, unsigned short* __restrict__ xb) {
  long e = ((long)blockIdx.x * 256 + threadIdx.x) * 8;   // grid sized exactly: X_PAD/8/256 blocks
  u16x8 o;
  if (e < X_REAL) {
    float4 f0 = *(const float4*)(x + e);
    float4 f1 = *(const float4*)(x + e + 4);
    o[0] = f2bf(f0.x); o[1] = f2bf(f0.y); o[2] = f2bf(f0.z); o[3] = f2bf(f0.w);
    o[4] = f2bf(f1.x); o[5] = f2bf(f1.y); o[6] = f2bf(f1.z); o[7] = f2bf(f1.w);
  } else {
    o = (u16x8)0;
  }
  *(u16x8*)(xb + e) = o;
}

// W [K][N] fp32 -> Wt [Npad][K] bf16 (rows >= N zero-filled)
__global__ void cvt_wt_kernel(const float* __restrict__ W, unsigned short* __restrict__ Wt,
                              int K, int N, int Npad) {
  int idx = blockIdx.x * 256 + threadIdx.x;
  if (idx >= Npad * K) return;
  int n = idx / K, k = idx % K;
  Wt[idx] = (n < N) ? f2bf(W[(long)k * N + n]) : (unsigned short)0;
}

__global__ void norms_kernel(const int* __restrict__ hist,
                             float* __restrict__ nsrc, float* __restrict__ ndst) {
  int i = blockIdx.x * 256 + threadIdx.x;
  if (i >= M_PAD) return;
  if (i < N_NODES) {
    nsrc[i] = rsqrtf(fmaxf((float)hist[N_NODES + i], 1.f));  // deg_out
    ndst[i] = rsqrtf(fmaxf((float)hist[i], 1.f));            // deg_in
  } else {
    nsrc[i] = 1.f;
  }
}

// ---------------- GEMM: C = A(bf16,[M_PAD][K]) x Bt(bf16,[Nfull][K])^T ----------------
// EPI 0: bf16( relu(acc + bias[col]) )
// EPI 1: bf16( relu(acc + bias[col]) * rowscale[row] )
// EPI 2: f32 raw acc (no bias)
// EDGES: blocks with blockIdx.x == gridDim.x-1 instead build the adjacency buckets +
//        degree histograms (atomic-latency-bound role overlapped with MFMA-bound GEMM;
//        interleaved in dispatch order -> co-resident with GEMM blocks).
template <int BM, int BN, int BK, int EPI, bool EDGES>
__launch_bounds__(256)
__global__ void gemm_bt(const unsigned short* __restrict__ A,
                        const unsigned short* __restrict__ Bt,
                        const float* __restrict__ bias,
                        const float* __restrict__ rowscale,
                        void* __restrict__ C, int K, int Nfull,
                        const int* __restrict__ esrc, const int* __restrict__ edst,
                        int* __restrict__ hist, int* __restrict__ bucket) {
  if constexpr (EDGES) {
    if (blockIdx.x == gridDim.x - 1) {
      const int stride = gridDim.y * 256;
      for (int e = blockIdx.y * 256 + threadIdx.x; e < N_EDGES; e += stride) {
        int s = esrc[e], d = edst[e];
        atomicAdd(&hist[N_NODES + s], 1);
        int p = atomicAdd(&hist[d], 1);
        if (p < BCAP) bucket[(size_t)d * BCAP + p] = s;
      }
      return;
    }
  }
  constexpr int WM = BM / 2, WN = BN / 2;
  constexpr int MI = WM / 16, NI = WN / 16;
  __shared__ __align__(16) unsigned short As[BM * BK];
  __shared__ __align__(16) unsigned short Bs[BN * BK];
  const int tid = threadIdx.x;
  const int wave = tid >> 6, lane = tid & 63;
  const int wm0 = (wave >> 1) * WM, wn0 = (wave & 1) * WN;
  const long rowBase = (long)blockIdx.y * BM;
  const int colBase = blockIdx.x * BN;
  const unsigned short* Ab = A + rowBase * K;
  const unsigned short* Bb = Bt + (long)colBase * K;
  f32x4 acc[MI][NI] = {};
  constexpr int ACH = BM * BK / 8;  // 16B chunks
  constexpr int BCH = BN * BK / 8;
  for (int k0 = 0; k0 < K; k0 += BK) {
#pragma unroll
    for (int c = tid; c < ACH; c += 256) {
      int r = (c * 8) / BK, cc = (c * 8) % BK;
      async_copy16(Ab + (long)r * K + k0 + cc, &As[c * 8]);
    }
#pragma unroll
    for (int c = tid; c < BCH; c += 256) {
      int r = (c * 8) / BK, cc = (c * 8) % BK;
      async_copy16(Bb + (long)r * K + k0 + cc, &Bs[c * 8]);
    }
    __syncthreads();
#pragma unroll
    for (int kk = 0; kk < BK; kk += 32) {
      bf16x8 af[MI], bfr[NI];
#pragma unroll
      for (int mi = 0; mi < MI; ++mi)
        af[mi] = *(const bf16x8*)&As[(wm0 + mi * 16 + (lane & 15)) * BK + kk + (lane >> 4) * 8];
#pragma unroll
      for (int ni = 0; ni < NI; ++ni)
        bfr[ni] = *(const bf16x8*)&Bs[(wn0 + ni * 16 + (lane & 15)) * BK + kk + (lane >> 4) * 8];
#pragma unroll
      for (int mi = 0; mi < MI; ++mi)
#pragma unroll
        for (int ni = 0; ni < NI; ++ni)
          acc[mi][ni] = __builtin_amdgcn_mfma_f32_16x16x32_bf16(af[mi], bfr[ni], acc[mi][ni], 0, 0, 0);
    }
    __syncthreads();
  }
  const int q = lane >> 4, c15 = lane & 15;
#pragma unroll
  for (int mi = 0; mi < MI; ++mi) {
#pragma unroll
    for (int ni = 0; ni < NI; ++ni) {
#pragma unroll
      for (int r = 0; r < 4; ++r) {
        long row = rowBase + wm0 + mi * 16 + q * 4 + r;
        int col = colBase + wn0 + ni * 16 + c15;
        float v = acc[mi][ni][r];
        if (EPI == 0) {
          v = fmaxf(v + bias[col], 0.f);
          ((unsigned short*)C)[row * Nfull + col] = f2bf(v);
        } else if (EPI == 1) {
          v = fmaxf(v + bias[col], 0.f) * rowscale[row];
          ((unsigned short*)C)[row * Nfull + col] = f2bf(v);
        } else {  // EPI == 2: raw f32
          ((float*)C)[row * Nfull + col] = v;
        }
      }
    }
  }
}

// ---------------- aggregation over f32 t-rows (GEMM-first order) ----------------
// acc = ndst[node] * sum_{s in bucket[node]} t[s][:]  ; v = relu(acc + bias)
// FINAL 0: gout[node][c] = bf16(v * nsrc[node])   (64 cols)
// FINAL 1: dout[node][c] = v                      (40 of 64 cols; t stride stays 64)
template <int FINAL>
__global__ void aggregate_kernel(const float* __restrict__ t,
                                 const int* __restrict__ bucket, const int* __restrict__ cnt,
                                 const float* __restrict__ ndst, const float* __restrict__ nsrc,
                                 const float* __restrict__ bias,
                                 unsigned short* __restrict__ gout, float* __restrict__ dout) {
  int node = blockIdx.x * 4 + (threadIdx.x >> 6);
  int lane = threadIdx.x & 63;
  int r = lane >> 4;
  int c = (lane & 15) * 4;
  int n = min(cnt[node], BCAP);
  const int* bk = bucket + (size_t)node * BCAP;
  float4 acc = make_float4(0.f, 0.f, 0.f, 0.f);
  for (int i = r; i < n; i += 4) {
    int s = bk[i];
    float4 v = *(const float4*)(t + (size_t)s * 64 + c);
    acc.x += v.x; acc.y += v.y; acc.z += v.z; acc.w += v.w;
  }
  acc.x += __shfl_xor(acc.x, 16); acc.y += __shfl_xor(acc.y, 16);
  acc.z += __shfl_xor(acc.z, 16); acc.w += __shfl_xor(acc.w, 16);
  acc.x += __shfl_xor(acc.x, 32); acc.y += __shfl_xor(acc.y, 32);
  acc.z += __shfl_xor(acc.z, 32); acc.w += __shfl_xor(acc.w, 32);
  if (r == 0) {
    float nd = ndst[node];
    float v0 = fmaxf(nd * acc.x + bias[c + 0], 0.f);
    float v1 = fmaxf(nd * acc.y + bias[c + 1], 0.f);
    float v2 = fmaxf(nd * acc.z + bias[c + 2], 0.f);
    float v3 = fmaxf(nd * acc.w + bias[c + 3], 0.f);
    if (FINAL) {
      if (c < 40) {  // c multiple of 4; 40 too, so the quad never straddles
        float* o = dout + (size_t)node * 40;
        o[c + 0] = v0; o[c + 1] = v1; o[c + 2] = v2; o[c + 3] = v3;
      }
    } else {
      float ns = nsrc[node];
      ushort4 o;
      o.x = f2bf(v0 * ns); o.y = f2bf(v1 * ns);
      o.z = f2bf(v2 * ns); o.w = f2bf(v3 * ns);
      *(ushort4*)(gout + (size_t)node * 64 + c) = o;
    }
  }
}

// ---------------- launch ----------------

extern "C" void kernel_launch(void* const* d_in, const int* in_sizes, int n_in,
                              void* d_out, int out_size, void* d_ws, size_t ws_size,
                              hipStream_t stream) {
  (void)in_sizes; (void)n_in; (void)out_size; (void)ws_size;
  const float* x   = (const float*)d_in[0];
  const int* esrc  = (const int*)d_in[1];
  const int* edst  = (const int*)d_in[2];
  const float* W1  = (const float*)d_in[3];  const float* b1  = (const float*)d_in[4];
  const float* W2  = (const float*)d_in[5];  const float* b2  = (const float*)d_in[6];
  const float* W3  = (const float*)d_in[7];  const float* b3  = (const float*)d_in[8];
  const float* Wg1 = (const float*)d_in[9];  const float* bg1 = (const float*)d_in[10];
  const float* Wg2 = (const float*)d_in[11]; const float* bg2 = (const float*)d_in[12];
  const float* Wg3 = (const float*)d_in[13]; const float* bg3 = (const float*)d_in[14];
  const float* Wg4 = (const float*)d_in[15]; const float* bg4 = (const float*)d_in[16];
  float* out = (float*)d_out;

  char* ws = (char*)d_ws;
  size_t off = 0;
  auto alloc = [&](size_t bytes) -> void* {
    void* p = ws + off;
    off += (bytes + 255) & ~(size_t)255;
    return p;
  };

  unsigned short* xb = (unsigned short*)alloc((size_t)M_PAD * 512 * 2);  // region0 (reused)
  unsigned short* h1 = (unsigned short*)alloc((size_t)M_PAD * 512 * 2);
  int*   bucket  = (int*)alloc((size_t)N_NODES * BCAP * 4);
  int*   hist    = (int*)alloc((size_t)2 * N_NODES * 4);  // ONE block, exact memset
  float* nsrc    = (float*)alloc((size_t)M_PAD * 4);
  float* ndst    = (float*)alloc((size_t)N_NODES * 4);
  unsigned short* W1t  = (unsigned short*)alloc(512 * 512 * 2);
  unsigned short* W2t  = (unsigned short*)alloc(256 * 512 * 2);
  unsigned short* W3t  = (unsigned short*)alloc(64 * 256 * 2);
  unsigned short* Wg1t = (unsigned short*)alloc(64 * 64 * 2);
  unsigned short* Wg2t = (unsigned short*)alloc(64 * 64 * 2);
  unsigned short* Wg3t = (unsigned short*)alloc(64 * 64 * 2);
  unsigned short* Wg4t = (unsigned short*)alloc(64 * 64 * 2);

  // region0 reuse (xb dead after layer-1 GEMM); sizes sum to exactly M_PAD*1024 B:
  unsigned short* h2 = xb;                                                     // M_PAD*256 bf16
  unsigned short* ga = (unsigned short*)((char*)xb + (size_t)M_PAD * 256 * 2); // M_PAD*64 bf16
  unsigned short* ab = (unsigned short*)((char*)ga + (size_t)M_PAD * 64 * 2);  // M_PAD*64 bf16
  float*          tb = (float*)((char*)ab + (size_t)M_PAD * 64 * 2);           // M_PAD*64 f32

  // 1) zero both histograms — exact size
  hipMemsetAsync(hist, 0, (size_t)2 * N_NODES * 4, stream);

  // 2) x -> bf16 padded (25024 blocks exactly cover X_PAD at 8 elems/thread)
  cvt_x_kernel<<<(int)(X_PAD / 8 / 256), 256, 0, stream>>>(x, xb);

  // 3) weights -> bf16 transposed [Npad][K]
  cvt_wt_kernel<<<(512 * 512 + 255) / 256, 256, 0, stream>>>(W1, W1t, 512, 512, 512);
  cvt_wt_kernel<<<(256 * 512 + 255) / 256, 256, 0, stream>>>(W2, W2t, 512, 256, 256);
  cvt_wt_kernel<<<(64 * 256 + 255) / 256, 256, 0, stream>>>(W3, W3t, 256, 64, 64);
  cvt_wt_kernel<<<(64 * 64 + 255) / 256, 256, 0, stream>>>(Wg1, Wg1t, 64, 64, 64);
  cvt_wt_kernel<<<(64 * 64 + 255) / 256, 256, 0, stream>>>(Wg2, Wg2t, 64, 64, 64);
  cvt_wt_kernel<<<(64 * 64 + 255) / 256, 256, 0, stream>>>(Wg3, Wg3t, 64, 64, 64);
  cvt_wt_kernel<<<(64 * 64 + 255) / 256, 256, 0, stream>>>(Wg4, Wg4t, 64, 40, 64);  // pad 40->64

  const int GY = M_PAD / 128;  // 782

  // 4) GEMM1 fused with edge-bucket build: grid x=0..3 GEMM cols, x=4 edge role.
  //    Edge blocks interleave every 5th in dispatch order -> co-resident with MFMA blocks.
  gemm_bt<128, 128, 64, 0, true><<<dim3(5, GY), 256, 0, stream>>>(
      xb, W1t, b1, nullptr, h1, 512, 512, esrc, edst, hist, bucket);

  // 5) norms (hist complete after fused dispatch)
  norms_kernel<<<(M_PAD + 255) / 256, 256, 0, stream>>>(hist, nsrc, ndst);

  // 6) rest of MLP
  gemm_bt<128, 128, 64, 0, false><<<dim3(2, GY), 256, 0, stream>>>(
      h1, W2t, b2, nullptr, h2, 512, 256, nullptr, nullptr, nullptr, nullptr);
  gemm_bt<128, 64, 64, 1, false><<<dim3(1, GY), 256, 0, stream>>>(
      h2, W3t, b3, nsrc, ga, 256, 64, nullptr, nullptr, nullptr, nullptr);

  // 7) GCN layers, GEMM-first (f32 t stride 64 ALWAYS, single bf16 rounding per layer):
  //    t = g @ Wg ; g' = bf16( nsrc * relu(ndst * segsum(t[src]) + b) )
  gemm_bt<128, 64, 64, 2, false><<<dim3(1, GY), 256, 0, stream>>>(
      ga, Wg1t, nullptr, nullptr, tb, 64, 64, nullptr, nullptr, nullptr, nullptr);
  aggregate_kernel<0><<<N_NODES / 4, 256, 0, stream>>>(tb, bucket, hist, ndst, nsrc, bg1, ab, nullptr);

  gemm_bt<128, 64, 64, 2, false><<<dim3(1, GY), 256, 0, stream>>>(
      ab, Wg2t, nullptr, nullptr, tb, 64, 64, nullptr, nullptr, nullptr, nullptr);
  aggregate_kernel<0><<<N_NODES / 4, 256, 0, stream>>>(tb, bucket, hist, ndst, nsrc, bg2, ga, nullptr);

  gemm_bt<128, 64, 64, 2, false><<<dim3(1, GY), 256, 0, stream>>>(
      ga, Wg3t, nullptr, nullptr, tb, 64, 64, nullptr, nullptr, nullptr, nullptr);
  aggregate_kernel<0><<<N_NODES / 4, 256, 0, stream>>>(tb, bucket, hist, ndst, nsrc, bg3, ab, nullptr);

  // final: Nfull=64 (padded weight cols are zero; aggregate masks lanes >= 40)
  gemm_bt<128, 64, 64, 2, false><<<dim3(1, GY), 256, 0, stream>>>(
      ab, Wg4t, nullptr, nullptr, tb, 64, 64, nullptr, nullptr, nullptr, nullptr);
  aggregate_kernel<1><<<N_NODES / 4, 256, 0, stream>>>(tb, bucket, hist, ndst, nsrc, bg4, nullptr, out);
}